// Round 1
// baseline (1229.474 us; speedup 1.0000x reference)
//
#include <hip/hip_runtime.h>
#include <hip/hip_bf16.h>

typedef __attribute__((ext_vector_type(8))) short short8;
typedef __attribute__((ext_vector_type(4))) float f32x4;
typedef unsigned short u16;

#define B_N 2
#define S_N 1024
#define HID_N 2048
#define NH_N 8
#define HD_N 256
#define INTER_N 16384

__device__ inline u16 f2b_rn(float f) {
    union { float f; unsigned int u; } x; x.f = f;
    unsigned int r = x.u + 0x7fffu + ((x.u >> 16) & 1u);
    return (u16)(r >> 16);
}
__device__ inline float b2f(u16 h) {
    union { unsigned int u; float f; } x; x.u = ((unsigned int)h) << 16;
    return x.f;
}
__device__ inline float gelu_tanh(float x) {
    float x3 = x * x * x;
    return 0.5f * x * (1.f + tanhf(0.7978845608028654f * (x + 0.044715f * x3)));
}

// ---------------- fp32 -> bf16 convert (grid-stride, float4) ----------------
__global__ __launch_bounds__(256) void convert_f2b(const float* __restrict__ in,
                                                   u16* __restrict__ out, int n4) {
    int i = blockIdx.x * 256 + threadIdx.x;
    int stride = gridDim.x * 256;
    for (; i < n4; i += stride) {
        float4 v = reinterpret_cast<const float4*>(in)[i];
        u16 o[4] = { f2b_rn(v.x), f2b_rn(v.y), f2b_rn(v.z), f2b_rn(v.w) };
        reinterpret_cast<ulonglong1*>(out)[i] = *reinterpret_cast<ulonglong1*>(o);
    }
}

// ---------------- RMSNorm: fp32 in -> bf16 out, one block per row ----------------
__global__ __launch_bounds__(256) void rmsnorm_k(const float* __restrict__ x,
                                                 const float* __restrict__ w,
                                                 u16* __restrict__ out) {
    const int row = blockIdx.x;
    const int tid = threadIdx.x;
    const float* xr = x + (size_t)row * HID_N;
    const float4* xr4 = reinterpret_cast<const float4*>(xr);
    float4 a = xr4[tid * 2], b = xr4[tid * 2 + 1];
    float s = a.x*a.x + a.y*a.y + a.z*a.z + a.w*a.w
            + b.x*b.x + b.y*b.y + b.z*b.z + b.w*b.w;
    for (int off = 32; off > 0; off >>= 1) s += __shfl_xor(s, off, 64);
    __shared__ float red[4];
    if ((tid & 63) == 0) red[tid >> 6] = s;
    __syncthreads();
    float tot = red[0] + red[1] + red[2] + red[3];
    float inv = rsqrtf(tot * (1.0f / HID_N) + 1e-6f);
    const float4* w4 = reinterpret_cast<const float4*>(w);
    float4 wa = w4[tid * 2], wb = w4[tid * 2 + 1];
    short8 o;
    o[0] = (short)f2b_rn(a.x * inv * (1.f + wa.x));
    o[1] = (short)f2b_rn(a.y * inv * (1.f + wa.y));
    o[2] = (short)f2b_rn(a.z * inv * (1.f + wa.z));
    o[3] = (short)f2b_rn(a.w * inv * (1.f + wa.w));
    o[4] = (short)f2b_rn(b.x * inv * (1.f + wb.x));
    o[5] = (short)f2b_rn(b.y * inv * (1.f + wb.y));
    o[6] = (short)f2b_rn(b.z * inv * (1.f + wb.z));
    o[7] = (short)f2b_rn(b.w * inv * (1.f + wb.w));
    reinterpret_cast<short8*>(out + (size_t)row * HID_N)[tid] = o;
}

// ---------------- QKV post: per-head RMS + RoPE + scale, write q/k/v bufs ----------------
__global__ __launch_bounds__(256) void qkv_post_k(const float* __restrict__ qkv,
                                                  const float* __restrict__ cosb,
                                                  const float* __restrict__ sinb,
                                                  const int* __restrict__ kvw,
                                                  const float* __restrict__ qn,
                                                  const float* __restrict__ kn,
                                                  u16* __restrict__ qb,
                                                  u16* __restrict__ kb,
                                                  u16* __restrict__ vt) {
    const int bs = blockIdx.x;
    const int b = bs >> 10, s = bs & 1023;
    const int tid = threadIdx.x;
    const float* row = qkv + (size_t)bs * 2560;
    __shared__ float buf[256];
    __shared__ float red[4];
    const int sdst = kvw[s];
    const float cv = cosb[s * 128 + (tid & 127)];
    const float sv = sinb[s * 128 + (tid & 127)];
    for (int vi = 0; vi < 9; ++vi) {
        float val = row[vi * 256 + tid];
        float ss = val * val;
        for (int off = 32; off > 0; off >>= 1) ss += __shfl_xor(ss, off, 64);
        __syncthreads();
        if ((tid & 63) == 0) red[tid >> 6] = ss;
        __syncthreads();
        float ms = (red[0] + red[1] + red[2] + red[3]) * (1.f / 256.f) + 1e-6f;
        const float* nw = (vi < 8) ? qn : kn;
        float nrm = val * rsqrtf(ms) * (1.f + nw[tid]);
        buf[tid] = nrm;
        __syncthreads();
        float o;
        if (tid < 128) o = buf[tid] * cv - buf[tid + 128] * sv;
        else           o = buf[tid - 128] * sv + buf[tid] * cv;
        if (vi < 8) {
            qb[(((size_t)(b * 8 + vi)) * 1024 + s) * 256 + tid] = f2b_rn(o * 0.0625f);
        } else {
            kb[((size_t)(b * 1024 + sdst)) * 256 + tid] = f2b_rn(o);
        }
    }
    float vv = row[2304 + tid];
    vt[((size_t)(b * 256 + tid)) * 1024 + sdst] = f2b_rn(vv);
}

// ---------------- Flash attention with tanh softcap (fixed m=0) ----------------
__global__ __launch_bounds__(256) void attn_k(const u16* __restrict__ qb,
                                              const u16* __restrict__ kb,
                                              const u16* __restrict__ vt,
                                              u16* __restrict__ out) {
    const int qt = blockIdx.x;   // 16 q-tiles of 64
    const int h  = blockIdx.y;   // 8 heads
    const int b  = blockIdx.z;   // 2 batch
    const int tid = threadIdx.x, lane = tid & 63, wid = tid >> 6;
    const int g = lane >> 4, li = lane & 15;
    const int q0 = qt * 64 + wid * 16;
    __shared__ u16 pbuf[4][16 * 32];

    short8 qf[8];
    const size_t qbase = (((size_t)(b * 8 + h)) * 1024 + q0 + li) * 256;
    #pragma unroll
    for (int kk = 0; kk < 8; ++kk)
        qf[kk] = *reinterpret_cast<const short8*>(qb + qbase + kk * 32 + g * 8);

    f32x4 o[16];
    #pragma unroll
    for (int d = 0; d < 16; ++d) o[d] = f32x4{0.f, 0.f, 0.f, 0.f};
    float lsum[4] = {0.f, 0.f, 0.f, 0.f};

    const int nt = (qt * 64 + 64) / 32;
    for (int t = 0; t < nt; ++t) {
        const int kv0 = t * 32;
        f32x4 sc[2];
        sc[0] = f32x4{0.f, 0.f, 0.f, 0.f};
        sc[1] = f32x4{0.f, 0.f, 0.f, 0.f};
        #pragma unroll
        for (int ch = 0; ch < 2; ++ch) {
            const size_t kbase = ((size_t)(b * 1024 + kv0 + ch * 16 + li)) * 256;
            #pragma unroll
            for (int kk = 0; kk < 8; ++kk) {
                short8 kf = *reinterpret_cast<const short8*>(kb + kbase + kk * 32 + g * 8);
                sc[ch] = __builtin_amdgcn_mfma_f32_16x16x32_bf16(qf[kk], kf, sc[ch], 0, 0, 0);
            }
        }
        float pv[2][4];
        #pragma unroll
        for (int reg = 0; reg < 4; ++reg) {
            int qrow = q0 + g * 4 + reg;
            float rs = 0.f;
            #pragma unroll
            for (int ch = 0; ch < 2; ++ch) {
                int col = kv0 + ch * 16 + li;
                float s = sc[ch][reg];
                s = tanhf(s * 0.02f) * 50.f;
                float p = (col <= qrow) ? exp2f(s * 1.44269504f) : 0.f;
                pv[ch][reg] = p;
                rs += p;
            }
            for (int off = 1; off < 16; off <<= 1) rs += __shfl_xor(rs, off, 64);
            lsum[reg] += rs;
        }
        __syncthreads();
        #pragma unroll
        for (int reg = 0; reg < 4; ++reg)
            #pragma unroll
            for (int ch = 0; ch < 2; ++ch)
                pbuf[wid][(g * 4 + reg) * 32 + ch * 16 + li] = f2b_rn(pv[ch][reg]);
        __syncthreads();
        short8 pf = *reinterpret_cast<const short8*>(&pbuf[wid][li * 32 + g * 8]);
        #pragma unroll
        for (int dt = 0; dt < 16; ++dt) {
            const size_t vbase = ((size_t)(b * 256 + dt * 16 + li)) * 1024 + kv0 + g * 8;
            short8 vf = *reinterpret_cast<const short8*>(vt + vbase);
            o[dt] = __builtin_amdgcn_mfma_f32_16x16x32_bf16(pf, vf, o[dt], 0, 0, 0);
        }
    }
    #pragma unroll
    for (int reg = 0; reg < 4; ++reg) {
        int row = q0 + g * 4 + reg;
        float inv = 1.f / lsum[reg];
        #pragma unroll
        for (int dt = 0; dt < 16; ++dt) {
            out[((size_t)(b * 1024 + row)) * 2048 + h * 256 + dt * 16 + li] =
                f2b_rn(o[dt][reg] * inv);
        }
    }
}

// ---------------- bf16 GEMM: C[M][N] = A[M][K] * W[N][K]^T, tile 128x128, BK=64 ----------------
// EPI: 0 = store f32, 1 = store f32 + residual, 2 = gelu -> bf16, 3 = mul gate -> bf16
template <int EPI>
__global__ __launch_bounds__(256) void gemm_bt(const u16* __restrict__ A,
                                               const u16* __restrict__ W,
                                               const float* __restrict__ res,
                                               const u16* __restrict__ gin,
                                               float* __restrict__ outf,
                                               u16* __restrict__ outb,
                                               int M, int N, int K) {
    __shared__ u16 As[128 * 64];
    __shared__ u16 Bs[128 * 64];
    const int tid = threadIdx.x, lane = tid & 63, wid = tid >> 6;
    const int g = lane >> 4, li = lane & 15;
    const int wr = wid >> 1, wc = wid & 1;
    const int m0 = blockIdx.x * 128, n0 = blockIdx.y * 128;
    f32x4 acc[4][4];
    #pragma unroll
    for (int m = 0; m < 4; ++m)
        #pragma unroll
        for (int n = 0; n < 4; ++n) acc[m][n] = f32x4{0.f, 0.f, 0.f, 0.f};

    const int sr = tid >> 3, sc8 = tid & 7;
    for (int k0 = 0; k0 < K; k0 += 64) {
        __syncthreads();
        #pragma unroll
        for (int p = 0; p < 4; ++p) {
            int r = sr + p * 32;
            short8 va = *reinterpret_cast<const short8*>(A + (size_t)(m0 + r) * K + k0 + sc8 * 8);
            *reinterpret_cast<short8*>(&As[r * 64 + ((sc8 ^ (r & 7)) * 8)]) = va;
            short8 vb = *reinterpret_cast<const short8*>(W + (size_t)(n0 + r) * K + k0 + sc8 * 8);
            *reinterpret_cast<short8*>(&Bs[r * 64 + ((sc8 ^ (r & 7)) * 8)]) = vb;
        }
        __syncthreads();
        #pragma unroll
        for (int kh = 0; kh < 2; ++kh) {
            short8 af[4], bf[4];
            #pragma unroll
            for (int m = 0; m < 4; ++m) {
                int rw = wr * 64 + m * 16 + li;
                int slot = (kh * 4 + g) ^ (rw & 7);
                af[m] = *reinterpret_cast<const short8*>(&As[rw * 64 + slot * 8]);
            }
            #pragma unroll
            for (int n = 0; n < 4; ++n) {
                int rw = wc * 64 + n * 16 + li;
                int slot = (kh * 4 + g) ^ (rw & 7);
                bf[n] = *reinterpret_cast<const short8*>(&Bs[rw * 64 + slot * 8]);
            }
            #pragma unroll
            for (int m = 0; m < 4; ++m)
                #pragma unroll
                for (int n = 0; n < 4; ++n)
                    acc[m][n] = __builtin_amdgcn_mfma_f32_16x16x32_bf16(af[m], bf[n], acc[m][n], 0, 0, 0);
        }
    }
    #pragma unroll
    for (int m = 0; m < 4; ++m) {
        #pragma unroll
        for (int n = 0; n < 4; ++n) {
            #pragma unroll
            for (int reg = 0; reg < 4; ++reg) {
                int row = m0 + wr * 64 + m * 16 + g * 4 + reg;
                int col = n0 + wc * 64 + n * 16 + li;
                size_t idx = (size_t)row * N + col;
                float v = acc[m][n][reg];
                if (EPI == 0) {
                    outf[idx] = v;
                } else if (EPI == 1) {
                    outf[idx] = v + res[idx];
                } else if (EPI == 2) {
                    outb[idx] = f2b_rn(gelu_tanh(v));
                } else {
                    outb[idx] = f2b_rn(v * b2f(gin[idx]));
                }
            }
        }
    }
}

extern "C" void kernel_launch(void* const* d_in, const int* in_sizes, int n_in,
                              void* d_out, int out_size, void* d_ws, size_t ws_size,
                              hipStream_t stream) {
    (void)in_sizes; (void)n_in; (void)out_size; (void)ws_size;
    const float* hs     = (const float*)d_in[0];
    const float* cosb   = (const float*)d_in[1];
    const float* sinb   = (const float*)d_in[2];
    const int*   kvw    = (const int*)d_in[3];
    const float* wqkv   = (const float*)d_in[7];
    const float* wo     = (const float*)d_in[8];
    const float* wg     = (const float*)d_in[9];
    const float* wu     = (const float*)d_in[10];
    const float* wd     = (const float*)d_in[11];
    const float* ln_in  = (const float*)d_in[12];
    const float* ln_post= (const float*)d_in[13];
    const float* qn     = (const float*)d_in[14];
    const float* kn     = (const float*)d_in[15];
    float* out = (float*)d_out;

    char* p = (char*)d_ws;
    auto alloc = [&](size_t bytes) {
        char* r = p;
        p += (bytes + 255) & ~(size_t)255;
        return r;
    };
    u16* wqkv_b = (u16*)alloc(2560ull * 2048 * 2);
    u16* wo_b   = (u16*)alloc(2048ull * 2048 * 2);
    u16* wg_b   = (u16*)alloc(16384ull * 2048 * 2);
    u16* wu_b   = (u16*)alloc(16384ull * 2048 * 2);
    u16* wd_b   = (u16*)alloc(2048ull * 16384 * 2);
    u16* xn     = (u16*)alloc(2048ull * 2048 * 2);
    float* qkvf = (float*)alloc(2048ull * 2560 * 4);
    u16* qbuf   = (u16*)alloc(2ull * 8 * 1024 * 256 * 2);
    u16* kbuf   = (u16*)alloc(2ull * 1024 * 256 * 2);
    u16* vtbuf  = (u16*)alloc(2ull * 256 * 1024 * 2);
    u16* attn_o = (u16*)alloc(2048ull * 2048 * 2);
    float* hbuf = (float*)alloc(2048ull * 2048 * 4);
    u16* x2     = (u16*)alloc(2048ull * 2048 * 2);
    u16* actb   = (u16*)alloc(2048ull * 16384 * 2);

    auto conv = [&](const float* src, u16* dst, long n) {
        int n4 = (int)(n / 4);
        long blk = (n4 + 255) / 256;
        if (blk > 4096) blk = 4096;
        convert_f2b<<<dim3((unsigned)blk), dim3(256), 0, stream>>>(src, dst, n4);
    };
    conv(wqkv, wqkv_b, 2560l * 2048);
    conv(wo,   wo_b,   2048l * 2048);
    conv(wg,   wg_b,   16384l * 2048);
    conv(wu,   wu_b,   16384l * 2048);
    conv(wd,   wd_b,   2048l * 16384);

    // x = RMSNorm(hidden, ln_in) -> bf16
    rmsnorm_k<<<dim3(2048), dim3(256), 0, stream>>>(hs, ln_in, xn);
    // qkv = x @ w_qkv^T -> fp32
    gemm_bt<0><<<dim3(16, 20), dim3(256), 0, stream>>>(xn, wqkv_b, nullptr, nullptr,
                                                       qkvf, nullptr, 2048, 2560, 2048);
    // per-head rms + rope + scale, k/v buffers
    qkv_post_k<<<dim3(2048), dim3(256), 0, stream>>>(qkvf, cosb, sinb, kvw, qn, kn,
                                                     qbuf, kbuf, vtbuf);
    // attention
    attn_k<<<dim3(16, 8, 2), dim3(256), 0, stream>>>(qbuf, kbuf, vtbuf, attn_o);
    // h = res + attn_out @ w_o^T
    gemm_bt<1><<<dim3(16, 16), dim3(256), 0, stream>>>(attn_o, wo_b, hs, nullptr,
                                                       hbuf, nullptr, 2048, 2048, 2048);
    // x2 = RMSNorm(h, ln_post) -> bf16
    rmsnorm_k<<<dim3(2048), dim3(256), 0, stream>>>(hbuf, ln_post, x2);
    // gate = gelu(x2 @ w_gate^T) -> bf16
    gemm_bt<2><<<dim3(16, 128), dim3(256), 0, stream>>>(x2, wg_b, nullptr, nullptr,
                                                        nullptr, actb, 2048, 16384, 2048);
    // act = (x2 @ w_up^T) * gate -> bf16 (in-place elementwise on actb)
    gemm_bt<3><<<dim3(16, 128), dim3(256), 0, stream>>>(x2, wu_b, nullptr, actb,
                                                        nullptr, actb, 2048, 16384, 2048);
    // out = h + act @ w_down^T
    gemm_bt<1><<<dim3(16, 16), dim3(256), 0, stream>>>(actb, wd_b, hbuf, nullptr,
                                                       out, nullptr, 2048, 2048, 16384);
}